// Round 9
// baseline (180.016 us; speedup 1.0000x reference)
//
#include <hip/hip_runtime.h>
#include <cstdint>
#include <cstddef>

// Problem constants
#define BB 64
#define TN 4096
#define FF 128
#define NBLK 256                 // cov blocks: 64 batches x 4 quarters, 1/CU
#define WROWS 256                // t-rows per wave
#define KT 32                    // rows per subtile (one MFMA K-step)
#define NST (WROWS / KT)         // 8 subtiles per wave

#define NTILE_UP 36
#define TILE_ELEMS 256
#define PART_FLOATS (NTILE_UP * TILE_ELEMS)   // 9216

#define WREG 9248                // per-wave LDS region bytes (2312 dwords)

// ws layout (floats)
#define SUM0_OFF 0
#define MEAN_OFF (SUM0_OFF + BB * FF)
#define RSTD_OFF (MEAN_OFF + BB * FF)
#define SABS_OFF (RSTD_OFF + BB * FF)
#define TRI_OFF  (SABS_OFF + 1)
#define DONE_OFF (TRI_OFF + 1)
#define ZERO_FLOATS (DONE_OFF + 1)
#define R_OFF 24832                           // [BB][9216]
#define P_OFF (R_OFF + BB * PART_FLOATS)      // [NBLK][9216]  (9.4 MB)

typedef __attribute__((ext_vector_type(8))) short bf16x8_t;
typedef __attribute__((ext_vector_type(4))) short short4_t;
typedef __attribute__((ext_vector_type(4))) float f32x4;

__device__ __constant__ int kRowBase[8] = {0, 8, 15, 21, 26, 30, 33, 35};
// tile index -> tr if diagonal tile else -1
__device__ __constant__ int kDiagTr[36] = {
    0,-1,-1,-1,-1,-1,-1,-1, 1,-1,-1,-1,-1,-1,-1, 2,-1,-1,-1,-1,-1,
    3,-1,-1,-1,-1, 4,-1,-1,-1, 5,-1,-1, 6,-1, 7};

static __device__ __forceinline__ unsigned f2bf(float f) {
    unsigned u = __builtin_bit_cast(unsigned, f);
    return (u + 0x7FFFu + ((u >> 16) & 1u)) >> 16;   // RNE
}
static __device__ __forceinline__ float elem(const float4& v, int j) {
    return reinterpret_cast<const float*>(&v)[j];    // j compile-time after unroll
}

#define VMWAIT(N) do { asm volatile("s_waitcnt vmcnt(" #N ")" ::: "memory"); \
                       __builtin_amdgcn_sched_barrier(0); } while (0)

// ---------------------------------------------------------------------------
// Kernel 1: wave-private bf16-MFMA syrk. 256 blocks x 256 thr, 1 block/CU.
// NO barriers in the main loop: each wave streams its own 256-row slice into
// its private 9 KB LDS transpose buffer and accumulates all 36 tiles.
// Reg-staged loads (asm, 2 sets) with per-wave counted vmcnt(8).
// Epilogue: cross-wave LDS reduction -> one P slice per block.
// ---------------------------------------------------------------------------
__global__ __launch_bounds__(256, 1) void cov_kernel(const float* __restrict__ x,
                                                     float* __restrict__ ws)
{
    __shared__ __align__(16) char lds[4 * WREG];   // ~37 KB

    const int b  = blockIdx.x >> 2;
    const int qt = blockIdx.x & 3;
    const int tid  = threadIdx.x;
    const int w    = tid >> 6;
    const int lane = tid & 63;
    const int m    = lane & 15;    // MFMA frag coords
    const int h    = lane >> 4;    // 0..3
    const int c    = lane & 31;    // staging f-quad
    const int hl   = lane >> 5;    // staging row-half

    char* T = lds + w * WREG;
    const float* xw = x + ((size_t)b * TN + qt * 1024 + w * WROWS) * FF;

    f32x4 acc[36];
#pragma unroll
    for (int i = 0; i < 36; ++i) acc[i] = (f32x4){0.f, 0.f, 0.f, 0.f};
    float csum[4] = {0.f, 0.f, 0.f, 0.f};
    float sabs = 0.f;

    float4 A0,A1,A2,A3,A4,A5,A6,A7;   // staging set A
    float4 B0,B1,B2,B3,B4,B5,B6,B7;   // staging set B

    // half hh (0..15): rows hh*16 + hl*8 + i, f-quad c
    auto issueA = [&](int hh) {
        const char* a = (const char*)xw + (size_t)(hh * 16 + hl * 8) * 512 + c * 16;
        asm volatile(
            "global_load_dwordx4 %0, %8, off\n\t"
            "global_load_dwordx4 %1, %8, off offset:512\n\t"
            "global_load_dwordx4 %2, %8, off offset:1024\n\t"
            "global_load_dwordx4 %3, %8, off offset:1536\n\t"
            "global_load_dwordx4 %4, %8, off offset:2048\n\t"
            "global_load_dwordx4 %5, %8, off offset:2560\n\t"
            "global_load_dwordx4 %6, %8, off offset:3072\n\t"
            "global_load_dwordx4 %7, %8, off offset:3584"
            : "=&v"(A0), "=&v"(A1), "=&v"(A2), "=&v"(A3),
              "=&v"(A4), "=&v"(A5), "=&v"(A6), "=&v"(A7)
            : "v"(a) : "memory");
    };
    auto issueB = [&](int hh) {
        const char* a = (const char*)xw + (size_t)(hh * 16 + hl * 8) * 512 + c * 16;
        asm volatile(
            "global_load_dwordx4 %0, %8, off\n\t"
            "global_load_dwordx4 %1, %8, off offset:512\n\t"
            "global_load_dwordx4 %2, %8, off offset:1024\n\t"
            "global_load_dwordx4 %3, %8, off offset:1536\n\t"
            "global_load_dwordx4 %4, %8, off offset:2048\n\t"
            "global_load_dwordx4 %5, %8, off offset:2560\n\t"
            "global_load_dwordx4 %6, %8, off offset:3072\n\t"
            "global_load_dwordx4 %7, %8, off offset:3584"
            : "=&v"(B0), "=&v"(B1), "=&v"(B2), "=&v"(B3),
              "=&v"(B4), "=&v"(B5), "=&v"(B6), "=&v"(B7)
            : "v"(a) : "memory");
    };

    // set A: kblk = hl (even half); set B: kblk = 2+hl (odd half)
    auto convertA = [&]() {
        const int sw = ((hl ^ (c & 3)) << 4);
#pragma unroll
        for (int j = 0; j < 4; ++j) {
            const float v0 = elem(A0,j), v1 = elem(A1,j), v2 = elem(A2,j), v3 = elem(A3,j),
                        v4 = elem(A4,j), v5 = elem(A5,j), v6 = elem(A6,j), v7 = elem(A7,j);
            csum[j] += ((v0+v1)+(v2+v3)) + ((v4+v5)+(v6+v7));
            sabs += ((fabsf(v0)+fabsf(v1))+(fabsf(v2)+fabsf(v3)))
                  + ((fabsf(v4)+fabsf(v5))+(fabsf(v6)+fabsf(v7)));
            char* dst = T + (c * 4 + j) * 72 + sw;
            *(uint2*)dst     = (uint2){f2bf(v0)|(f2bf(v1)<<16), f2bf(v2)|(f2bf(v3)<<16)};
            *(uint2*)(dst+8) = (uint2){f2bf(v4)|(f2bf(v5)<<16), f2bf(v6)|(f2bf(v7)<<16)};
        }
    };
    auto convertB = [&]() {
        const int sw = (((2 + hl) ^ (c & 3)) << 4);
#pragma unroll
        for (int j = 0; j < 4; ++j) {
            const float v0 = elem(B0,j), v1 = elem(B1,j), v2 = elem(B2,j), v3 = elem(B3,j),
                        v4 = elem(B4,j), v5 = elem(B5,j), v6 = elem(B6,j), v7 = elem(B7,j);
            csum[j] += ((v0+v1)+(v2+v3)) + ((v4+v5)+(v6+v7));
            sabs += ((fabsf(v0)+fabsf(v1))+(fabsf(v2)+fabsf(v3)))
                  + ((fabsf(v4)+fabsf(v5))+(fabsf(v6)+fabsf(v7)));
            char* dst = T + (c * 4 + j) * 72 + sw;
            *(uint2*)dst     = (uint2){f2bf(v0)|(f2bf(v1)<<16), f2bf(v2)|(f2bf(v3)<<16)};
            *(uint2*)(dst+8) = (uint2){f2bf(v4)|(f2bf(v5)<<16), f2bf(v6)|(f2bf(v7)<<16)};
        }
    };

    // ---- main loop: per wave, zero barriers ----
    issueA(0);
#pragma unroll 1
    for (int st = 0; st < NST; ++st) {
        issueB(2 * st + 1);
        VMWAIT(8);               // set A landed; B stays in flight
        convertA();
        if (st < NST - 1) {
            issueA(2 * st + 2);
            VMWAIT(8);           // set B landed; next A stays in flight
        } else {
            VMWAIT(0);
        }
        convertB();
        // frags (k contiguous per 16B block; XOR-swizzled)
        bf16x8_t F[8];
#pragma unroll
        for (int i = 0; i < 8; ++i) {
            const char* p = T + (i * 16 + m) * 72 + ((h ^ (m >> 2)) << 4);
            short4_t lo = *(const short4_t*)p;
            short4_t hi = *(const short4_t*)(p + 8);
            F[i] = (bf16x8_t){lo.x,lo.y,lo.z,lo.w,hi.x,hi.y,hi.z,hi.w};
        }
#pragma unroll
        for (int i = 0; i < 8; ++i)
#pragma unroll
            for (int j = i; j < 8; ++j)
                acc[kRowBase[i] + (j - i)] =
                    __builtin_amdgcn_mfma_f32_16x16x32_bf16(F[i], F[j],
                        acc[kRowBase[i] + (j - i)], 0, 0, 0);
    }

    // ---- epilogue: column sums + sum|x| ----
#pragma unroll
    for (int j = 0; j < 4; ++j) csum[j] += __shfl_down(csum[j], 32, 64);
#pragma unroll
    for (int off = 32; off > 0; off >>= 1) sabs += __shfl_down(sabs, off, 64);
    __syncthreads();             // all waves done with T
    if (lane < 32) {
#pragma unroll
        for (int j = 0; j < 4; ++j) ((float*)T)[c * 4 + j] = csum[j];
    }
    if (lane == 0) ((float*)T)[128] = sabs;
    __syncthreads();
    if (tid < FF) {
        float s = 0.f;
#pragma unroll
        for (int w4 = 0; w4 < 4; ++w4) s += ((float*)(lds + w4 * WREG))[tid];
        atomicAdd(&ws[SUM0_OFF + b * FF + tid], s);
    }
    if (tid == 0) {
        float s = 0.f;
#pragma unroll
        for (int w4 = 0; w4 < 4; ++w4) s += ((float*)(lds + w4 * WREG))[128];
        atomicAdd(&ws[SABS_OFF], s);
    }

    // ---- epilogue: cross-wave tile reduction, 4 passes x 9 tiles ----
    float* Pb = ws + P_OFF + (size_t)blockIdx.x * PART_FLOATS;
#pragma unroll
    for (int pass = 0; pass < 4; ++pass) {
        __syncthreads();
        float* q = (float*)lds + w * 2312;
#pragma unroll
        for (int tt = 0; tt < 9; ++tt) {
            const int t = pass * 9 + tt;
#pragma unroll
            for (int qq = 0; qq < 4; ++qq)
                q[tt * 256 + (h * 4 + qq) * 16 + m] = acc[t][qq];
        }
        __syncthreads();
#pragma unroll
        for (int e = 0; e < 9; ++e) {
            const int idx = e * 256 + tid;
            float s = 0.f;
#pragma unroll
            for (int w4 = 0; w4 < 4; ++w4) s += ((float*)lds)[w4 * 2312 + idx];
            Pb[pass * 2304 + idx] = s;
        }
    }
}

// ---------------------------------------------------------------------------
// Kernel 2: reduce 4 quarter-partials -> R, fused mean/rstd for diag tiles.
// ---------------------------------------------------------------------------
__global__ __launch_bounds__(256) void reduce_stats_kernel(float* __restrict__ ws)
{
    const int bb = blockIdx.x / NTILE_UP;
    const int t  = blockIdx.x % NTILE_UP;
    const int e  = t * 256 + threadIdx.x;
    const float* P = ws + P_OFF + (size_t)bb * 4 * PART_FLOATS + e;
    const float a = (P[0] + P[PART_FLOATS]) + (P[2*PART_FLOATS] + P[3*PART_FLOATS]);
    ws[R_OFF + (size_t)bb * PART_FLOATS + e] = a;

    const int tr = kDiagTr[t];
    if (tr >= 0) {
        const int i = threadIdx.x >> 4, j = threadIdx.x & 15;
        if (i == j) {
            const int idx = bb * FF + tr * 16 + i;
            const float mean = ws[SUM0_OFF + idx] * (1.f / TN);
            const float var  = a * (1.f / TN) - mean * mean;
            ws[MEAN_OFF + idx] = mean;
            ws[RSTD_OFF + idx] = rsqrtf(fmaxf(var, 1e-30f));
        }
    }
}

// ---------------------------------------------------------------------------
// Kernel 3: corr_avg_abs + strict upper-tri sum; last block writes outputs.
// ---------------------------------------------------------------------------
__global__ __launch_bounds__(256) void corr_final_kernel(float* __restrict__ ws,
                                                         float* __restrict__ out)
{
    __shared__ float red[4];
    const int p = blockIdx.x * 256 + threadIdx.x;   // 0..16383
    const int f = p >> 7, g = p & 127;

    float v = 0.f;
    if (g > f) {
        const int tidx = kRowBase[f >> 4] + ((g >> 4) - (f >> 4));
        const size_t off = (size_t)tidx * TILE_ELEMS + (f & 15) * 16 + (g & 15);
        float accum = 0.f;
#pragma unroll 8
        for (int b = 0; b < BB; ++b) {
            const float s2 = ws[R_OFF + (size_t)b * PART_FLOATS + off];
            const float mf = ws[MEAN_OFF + b * FF + f];
            const float mg = ws[MEAN_OFF + b * FF + g];
            const float rf = ws[RSTD_OFF + b * FF + f];
            const float rg = ws[RSTD_OFF + b * FF + g];
            accum += (s2 * (1.f / TN) - mf * mg) * rf * rg;
        }
        v = fabsf(accum * (1.f / BB));
    }

#pragma unroll
    for (int off = 32; off > 0; off >>= 1) v += __shfl_down(v, off, 64);
    const int lane = threadIdx.x & 63, wid = threadIdx.x >> 6;
    if (lane == 0) red[wid] = v;
    __syncthreads();
    if (threadIdx.x == 0) {
        atomicAdd(&ws[TRI_OFF], (red[0] + red[1]) + (red[2] + red[3]));
        __threadfence();
        const float old = atomicAdd(&ws[DONE_OFF], 1.0f);
        if (old == 63.0f) {                       // last block: publish outputs
            const float tri  = atomicAdd(&ws[TRI_OFF], 0.0f);
            const float sabs = ws[SABS_OFF];
            out[0] = tri * (0.01f / 8128.f);
            out[1] = tri;
            out[2] = sabs * (1.f / FF);
        }
    }
}

extern "C" void kernel_launch(void* const* d_in, const int* in_sizes, int n_in,
                              void* d_out, int out_size, void* d_ws, size_t ws_size,
                              hipStream_t stream)
{
    const float* x = (const float*)d_in[0];
    float* out = (float*)d_out;
    float* ws = (float*)d_ws;

    (void)hipMemsetAsync(d_ws, 0, (size_t)ZERO_FLOATS * sizeof(float), stream);

    hipLaunchKernelGGL(cov_kernel,          dim3(NBLK), dim3(256), 0, stream, x, ws);
    hipLaunchKernelGGL(reduce_stats_kernel, dim3(BB * NTILE_UP), dim3(256), 0, stream, ws);
    hipLaunchKernelGGL(corr_final_kernel,   dim3((FF * FF) / 256), dim3(256), 0, stream, ws, out);
}

// Round 11
// 56.334 us; speedup vs baseline: 3.1955x; 3.1955x over previous
//
#include <hip/hip_runtime.h>
#include <cstdint>
#include <cstddef>

// Problem constants
#define BB 64
#define TN 4096
#define FF 128
#define NBLK 256                 // cov blocks: 64 batches x 4 quarters, 1/CU
#define WROWS 256                // t-rows per wave
#define NST 8                    // 8 subtiles (32 rows each) per wave

#define NTILE_UP 36
#define TILE_ELEMS 256
#define PART_FLOATS (NTILE_UP * TILE_ELEMS)   // 9216

#define WREG 9248                // per-wave LDS region bytes (2312 dwords)

// ws layout (floats)
#define SUM0_OFF 0
#define MEAN_OFF (SUM0_OFF + BB * FF)
#define RSTD_OFF (MEAN_OFF + BB * FF)
#define SABS_OFF (RSTD_OFF + BB * FF)
#define TRI_OFF  (SABS_OFF + 1)
#define DONE_OFF (TRI_OFF + 1)
#define ZERO_FLOATS (DONE_OFF + 1)
#define R_OFF 24832                           // [BB][9216]
#define P_OFF (R_OFF + BB * PART_FLOATS)      // [NBLK][9216]  (9.4 MB)

typedef __attribute__((ext_vector_type(8))) short bf16x8_t;
typedef __attribute__((ext_vector_type(4))) short short4_t;
typedef __attribute__((ext_vector_type(4))) float f32x4;

// upper-tri tile index, compile-time foldable (no array, rule #20-safe)
__host__ __device__ constexpr int rbase(int i) { return i * 8 - (i * (i - 1)) / 2; }

// runtime tables for the small follow-up kernels only
__device__ __constant__ int kRowBaseRT[8] = {0, 8, 15, 21, 26, 30, 33, 35};
__device__ __constant__ int kDiagTr[36] = {
    0,-1,-1,-1,-1,-1,-1,-1, 1,-1,-1,-1,-1,-1,-1, 2,-1,-1,-1,-1,-1,
    3,-1,-1,-1,-1, 4,-1,-1,-1, 5,-1,-1, 6,-1, 7};

static __device__ __forceinline__ unsigned f2bf(float f) {
    unsigned u = __builtin_bit_cast(unsigned, f);
    return (u + 0x7FFFu + ((u >> 16) & 1u)) >> 16;   // RNE
}
static __device__ __forceinline__ float elem(const float4& v, int j) {
    return reinterpret_cast<const float*>(&v)[j];    // j compile-time after unroll
}

// ---------------------------------------------------------------------------
// Kernel 1: wave-private bf16-MFMA syrk. 256 blocks x 256 thr, 1 block/CU.
// NO barriers and NO inline asm in the main loop: plain float4 loads into
// named local arrays (SROA -> VGPRs), one set issued ahead; compiler emits
// counted waitcnts from dataflow. acc[] statically indexed -> VGPRs.
// ---------------------------------------------------------------------------
__global__ __launch_bounds__(256, 1) void cov_kernel(const float* __restrict__ x,
                                                     float* __restrict__ ws)
{
    __shared__ __align__(16) char lds[4 * WREG];   // ~37 KB

    const int b  = blockIdx.x >> 2;
    const int qt = blockIdx.x & 3;
    const int tid  = threadIdx.x;
    const int w    = tid >> 6;
    const int lane = tid & 63;
    const int m    = lane & 15;    // MFMA frag coords
    const int h    = lane >> 4;    // 0..3
    const int c    = lane & 31;    // staging f-quad
    const int hl   = lane >> 5;    // staging row-half

    char* T = lds + w * WREG;
    const float* xw = x + ((size_t)b * TN + qt * 1024 + w * WROWS) * FF;

    f32x4 acc[36];
#pragma unroll
    for (int i = 0; i < 36; ++i) acc[i] = (f32x4){0.f, 0.f, 0.f, 0.f};
    float csum[4] = {0.f, 0.f, 0.f, 0.f};
    float sabs = 0.f;

    float4 A[8], B[8];             // two staging sets, static-indexed

    // half hh (0..15): lane loads 8 rows (hh*16 + hl*8 + i) x 16B f-quad c
    auto load = [&](int hh, float4* dst) {
        const char* a = (const char*)xw + (size_t)(hh * 16 + hl * 8) * 512 + c * 16;
#pragma unroll
        for (int i = 0; i < 8; ++i)
            dst[i] = *(const float4*)(a + (size_t)i * 512);
    };

    // kblk kb (0..3): store 8 rows' bf16 at XOR-swizzled 16B column
    auto convert = [&](const float4* s, int kb) {
        const int sw = ((kb ^ (c & 3)) << 4);
#pragma unroll
        for (int j = 0; j < 4; ++j) {
            const float v0 = elem(s[0],j), v1 = elem(s[1],j), v2 = elem(s[2],j),
                        v3 = elem(s[3],j), v4 = elem(s[4],j), v5 = elem(s[5],j),
                        v6 = elem(s[6],j), v7 = elem(s[7],j);
            csum[j] += ((v0+v1)+(v2+v3)) + ((v4+v5)+(v6+v7));
            sabs += ((fabsf(v0)+fabsf(v1))+(fabsf(v2)+fabsf(v3)))
                  + ((fabsf(v4)+fabsf(v5))+(fabsf(v6)+fabsf(v7)));
            char* dst = T + (c * 4 + j) * 72 + sw;
            *(uint2*)dst     = (uint2){f2bf(v0)|(f2bf(v1)<<16), f2bf(v2)|(f2bf(v3)<<16)};
            *(uint2*)(dst+8) = (uint2){f2bf(v4)|(f2bf(v5)<<16), f2bf(v6)|(f2bf(v7)<<16)};
        }
    };

    // ---- main loop: per wave, zero barriers ----
    load(0, A);
    load(1, B);
#pragma unroll 1
    for (int st = 0; st < NST; ++st) {
        convert(A, hl);                       // k rows st*32 + hl*8 ..
        if (st < NST - 1) load(2 * st + 2, A);
        convert(B, 2 + hl);
        if (st < NST - 1) load(2 * st + 3, B);

        // frags (k contiguous per 16B block; XOR-swizzled by row/4)
        bf16x8_t F[8];
#pragma unroll
        for (int i = 0; i < 8; ++i) {
            const char* p = T + (i * 16 + m) * 72 + ((h ^ (m >> 2)) << 4);
            short4_t lo = *(const short4_t*)p;
            short4_t hi = *(const short4_t*)(p + 8);
            F[i] = (bf16x8_t){lo.x,lo.y,lo.z,lo.w,hi.x,hi.y,hi.z,hi.w};
        }
#pragma unroll
        for (int i = 0; i < 8; ++i)
#pragma unroll
            for (int j = i; j < 8; ++j)
                acc[rbase(i) + (j - i)] =
                    __builtin_amdgcn_mfma_f32_16x16x32_bf16(F[i], F[j],
                        acc[rbase(i) + (j - i)], 0, 0, 0);
    }

    // ---- epilogue: column sums + sum|x| ----
#pragma unroll
    for (int j = 0; j < 4; ++j) csum[j] += __shfl_down(csum[j], 32, 64);
#pragma unroll
    for (int off = 32; off > 0; off >>= 1) sabs += __shfl_down(sabs, off, 64);
    __syncthreads();             // all waves done with T
    if (lane < 32) {
#pragma unroll
        for (int j = 0; j < 4; ++j) ((float*)T)[c * 4 + j] = csum[j];
    }
    if (lane == 0) ((float*)T)[128] = sabs;
    __syncthreads();
    if (tid < FF) {
        float s = 0.f;
#pragma unroll
        for (int w4 = 0; w4 < 4; ++w4) s += ((float*)(lds + w4 * WREG))[tid];
        atomicAdd(&ws[SUM0_OFF + b * FF + tid], s);
    }
    if (tid == 0) {
        float s = 0.f;
#pragma unroll
        for (int w4 = 0; w4 < 4; ++w4) s += ((float*)(lds + w4 * WREG))[128];
        atomicAdd(&ws[SABS_OFF], s);
    }

    // ---- epilogue: cross-wave tile reduction, 4 passes x 9 tiles ----
    float* Pb = ws + P_OFF + (size_t)blockIdx.x * PART_FLOATS;
#pragma unroll
    for (int pass = 0; pass < 4; ++pass) {
        __syncthreads();
        float* q = (float*)lds + w * 2312;
#pragma unroll
        for (int tt = 0; tt < 9; ++tt) {
            const int t = pass * 9 + tt;
#pragma unroll
            for (int qq = 0; qq < 4; ++qq)
                q[tt * 256 + (h * 4 + qq) * 16 + m] = acc[t][qq];
        }
        __syncthreads();
#pragma unroll
        for (int e = 0; e < 9; ++e) {
            const int idx = e * 256 + tid;
            float s = 0.f;
#pragma unroll
            for (int w4 = 0; w4 < 4; ++w4) s += ((float*)lds)[w4 * 2312 + idx];
            Pb[pass * 2304 + idx] = s;
        }
    }
}

// ---------------------------------------------------------------------------
// Kernel 2: reduce 4 quarter-partials -> R, fused mean/rstd for diag tiles.
// ---------------------------------------------------------------------------
__global__ __launch_bounds__(256) void reduce_stats_kernel(float* __restrict__ ws)
{
    const int bb = blockIdx.x / NTILE_UP;
    const int t  = blockIdx.x % NTILE_UP;
    const int e  = t * 256 + threadIdx.x;
    const float* P = ws + P_OFF + (size_t)bb * 4 * PART_FLOATS + e;
    const float a = (P[0] + P[PART_FLOATS]) + (P[2*PART_FLOATS] + P[3*PART_FLOATS]);
    ws[R_OFF + (size_t)bb * PART_FLOATS + e] = a;

    const int tr = kDiagTr[t];
    if (tr >= 0) {
        const int i = threadIdx.x >> 4, j = threadIdx.x & 15;
        if (i == j) {
            const int idx = bb * FF + tr * 16 + i;
            const float mean = ws[SUM0_OFF + idx] * (1.f / TN);
            const float var  = a * (1.f / TN) - mean * mean;
            ws[MEAN_OFF + idx] = mean;
            ws[RSTD_OFF + idx] = rsqrtf(fmaxf(var, 1e-30f));
        }
    }
}

// ---------------------------------------------------------------------------
// Kernel 3: corr_avg_abs + strict upper-tri sum; last block writes outputs.
// ---------------------------------------------------------------------------
__global__ __launch_bounds__(256) void corr_final_kernel(float* __restrict__ ws,
                                                         float* __restrict__ out)
{
    __shared__ float red[4];
    const int p = blockIdx.x * 256 + threadIdx.x;   // 0..16383
    const int f = p >> 7, g = p & 127;

    float v = 0.f;
    if (g > f) {
        const int tidx = kRowBaseRT[f >> 4] + ((g >> 4) - (f >> 4));
        const size_t off = (size_t)tidx * TILE_ELEMS + (f & 15) * 16 + (g & 15);
        float accum = 0.f;
#pragma unroll 8
        for (int b = 0; b < BB; ++b) {
            const float s2 = ws[R_OFF + (size_t)b * PART_FLOATS + off];
            const float mf = ws[MEAN_OFF + b * FF + f];
            const float mg = ws[MEAN_OFF + b * FF + g];
            const float rf = ws[RSTD_OFF + b * FF + f];
            const float rg = ws[RSTD_OFF + b * FF + g];
            accum += (s2 * (1.f / TN) - mf * mg) * rf * rg;
        }
        v = fabsf(accum * (1.f / BB));
    }

#pragma unroll
    for (int off = 32; off > 0; off >>= 1) v += __shfl_down(v, off, 64);
    const int lane = threadIdx.x & 63, wid = threadIdx.x >> 6;
    if (lane == 0) red[wid] = v;
    __syncthreads();
    if (threadIdx.x == 0) {
        atomicAdd(&ws[TRI_OFF], (red[0] + red[1]) + (red[2] + red[3]));
        __threadfence();
        const float old = atomicAdd(&ws[DONE_OFF], 1.0f);
        if (old == 63.0f) {                       // last block: publish outputs
            const float tri  = atomicAdd(&ws[TRI_OFF], 0.0f);
            const float sabs = ws[SABS_OFF];
            out[0] = tri * (0.01f / 8128.f);
            out[1] = tri;
            out[2] = sabs * (1.f / FF);
        }
    }
}

extern "C" void kernel_launch(void* const* d_in, const int* in_sizes, int n_in,
                              void* d_out, int out_size, void* d_ws, size_t ws_size,
                              hipStream_t stream)
{
    const float* x = (const float*)d_in[0];
    float* out = (float*)d_out;
    float* ws = (float*)d_ws;

    (void)hipMemsetAsync(d_ws, 0, (size_t)ZERO_FLOATS * sizeof(float), stream);

    hipLaunchKernelGGL(cov_kernel,          dim3(NBLK), dim3(256), 0, stream, x, ws);
    hipLaunchKernelGGL(reduce_stats_kernel, dim3(BB * NTILE_UP), dim3(256), 0, stream, ws);
    hipLaunchKernelGGL(corr_final_kernel,   dim3((FF * FF) / 256), dim3(256), 0, stream, ws, out);
}